// Round 5
// baseline (818.683 us; speedup 1.0000x reference)
//
#include <hip/hip_runtime.h>
#include <hip/hip_bf16.h>
#include <climits>

// out[csr[i]] += x[ptrs[i]]
//   X_SIZE = 8,388,608 f32 (32 MB), NNZ = 33,554,432, N_SEG = 8,388,608, csr SORTED.
//
// R4 post-mortem: binned gather is L2-resident, but flushing per-bucket LDS
// tiles into `out` via device atomics = ~26M cross-XCD RMWs (WRITE 274 MB,
// phaseD 386 us). This round: zero global atomics in phase D.
//   - 4 csr-contiguous passes over fixed NNZ quarters (disjoint out slices).
//   - Per pass: A count / B scan / C stable 8-way bin by ptr>>20
//     / D gather into per-bucket DENSE PARTIALS (plain nt stores; chunk
//     ownership is segment-aligned via trim/extend, gaps zero-filled)
//     / E sum 8 partials -> out (streaming; atomics only at the 2 pass-
//     boundary segments).
//   ws need ~143 MB (proven available: R4 ran with 269 MB).

#define THREADS 256
#define PER_THREAD 16
#define EPB (THREADS * PER_THREAD)   // 4096 entries per block/chunk
#define NB 8                         // ptr slices of 4 MB (= one XCD L2)
#define NPASS 4
#define LDS_SEGS_FB 4096
#define LDS_SEGS_D 12288             // 48 KB -> 3 blocks/CU; span ~8192+-128

typedef int vint4 __attribute__((ext_vector_type(4)));
typedef int vint2 __attribute__((ext_vector_type(2)));

__device__ __forceinline__ int pad8(int t) { return (t + 7) & ~7; }

// ---------------------------------------------------------------- Phase A
__global__ __launch_bounds__(THREADS) void phaseA_count(
    const int* __restrict__ ptrs, int* __restrict__ counts, int shift)
{
    __shared__ unsigned long long cLo, cHi;
    const int tid = threadIdx.x;
    if (tid == 0) { cLo = 0ull; cHi = 0ull; }
    __syncthreads();

    const long long base = (long long)blockIdx.x * EPB + (long long)tid * PER_THREAD;
    const vint4* p4 = (const vint4*)(ptrs + base);
    unsigned long long lo = 0, hi = 0;
#pragma unroll
    for (int k = 0; k < PER_THREAD / 4; ++k) {
        vint4 a = __builtin_nontemporal_load(p4 + k);
#pragma unroll
        for (int e = 0; e < 4; ++e) {
            int pv = (e == 0) ? a.x : (e == 1) ? a.y : (e == 2) ? a.z : a.w;
            int b = pv >> shift; b = b > (NB - 1) ? (NB - 1) : b;
            unsigned long long one = 1ull << (16 * (b & 3));
            if (b < 4) lo += one; else hi += one;
        }
    }
    atomicAdd(&cLo, lo);
    atomicAdd(&cHi, hi);
    __syncthreads();
    if (tid < 4)
        counts[blockIdx.x * NB + tid] = (int)((cLo >> (16 * tid)) & 0xFFFFull);
    else if (tid < 8)
        counts[blockIdx.x * NB + tid] = (int)((cHi >> (16 * (tid - 4))) & 0xFFFFull);
}

// ---------------------------------------------------------------- Phase B
__global__ __launch_bounds__(THREADS) void phaseB_scan(
    const int* __restrict__ counts, int* __restrict__ offB,
    int* __restrict__ totals, int nblocks)
{
    __shared__ int wsum[THREADS / 64];
    const int b = blockIdx.x;
    const int tid = threadIdx.x, lane = tid & 63, wid = tid >> 6;
    const int per = nblocks / THREADS;
    const int start = tid * per;

    int s = 0;
    for (int i = 0; i < per; ++i) s += counts[(start + i) * NB + b];

    int inc = s;
#pragma unroll
    for (int d = 1; d < 64; d <<= 1) {
        int t = __shfl_up(inc, d);
        if (lane >= d) inc += t;
    }
    if (lane == 63) wsum[wid] = inc;
    __syncthreads();
    int wbase = 0;
    for (int w = 0; w < wid; ++w) wbase += wsum[w];
    int run = wbase + inc - s;

    for (int i = 0; i < per; ++i) {
        int c = counts[(start + i) * NB + b];
        offB[(start + i) * NB + b] = run;
        run += c;
    }
    if (tid == THREADS - 1) totals[b] = run;
}

// ---------------------------------------------------------------- Phase C
__global__ __launch_bounds__(THREADS) void phaseC_scatter(
    const int* __restrict__ ptrs, const int* __restrict__ csr,
    const int* __restrict__ offB, const int* __restrict__ totals,
    int* __restrict__ pairs, int shift)
{
    __shared__ int2 buf[EPB];                                   // 32 KB
    __shared__ unsigned long long wLo[THREADS / 64], wHi[THREADS / 64];
    __shared__ long long s_goff[NB];

    const int tid = threadIdx.x, lane = tid & 63, wid = tid >> 6;
    const long long base = (long long)blockIdx.x * EPB + (long long)tid * PER_THREAD;

    const vint4* p4 = (const vint4*)(ptrs + base);
    const vint4* c4 = (const vint4*)(csr + base);
    int p[PER_THREAD], c[PER_THREAD];
#pragma unroll
    for (int k = 0; k < PER_THREAD / 4; ++k) {
        vint4 a = __builtin_nontemporal_load(p4 + k);
        vint4 b = __builtin_nontemporal_load(c4 + k);
        p[4 * k + 0] = a.x; p[4 * k + 1] = a.y; p[4 * k + 2] = a.z; p[4 * k + 3] = a.w;
        c[4 * k + 0] = b.x; c[4 * k + 1] = b.y; c[4 * k + 2] = b.z; c[4 * k + 3] = b.w;
    }

    unsigned long long lo = 0, hi = 0;
#pragma unroll
    for (int j = 0; j < PER_THREAD; ++j) {
        int b = p[j] >> shift; b = b > (NB - 1) ? (NB - 1) : b;
        unsigned long long one = 1ull << (16 * (b & 3));
        if (b < 4) lo += one; else hi += one;
    }

    unsigned long long vLo = lo, vHi = hi;
#pragma unroll
    for (int d = 1; d < 64; d <<= 1) {
        unsigned long long tLo = __shfl_up(vLo, (unsigned)d);
        unsigned long long tHi = __shfl_up(vHi, (unsigned)d);
        if (lane >= d) { vLo += tLo; vHi += tHi; }
    }
    if (lane == 63) { wLo[wid] = vLo; wHi[wid] = vHi; }

    if (tid < NB) {
        long long bs = 0;
        for (int i = 0; i < tid; ++i) bs += pad8(totals[i]);
        s_goff[tid] = bs + offB[blockIdx.x * NB + tid];
    }
    __syncthreads();

    unsigned long long wbLo = 0, wbHi = 0, gLo = 0, gHi = 0;
#pragma unroll
    for (int w = 0; w < THREADS / 64; ++w) {
        if (w < wid) { wbLo += wLo[w]; wbHi += wHi[w]; }
        gLo += wLo[w]; gHi += wHi[w];
    }
    const unsigned long long exLo = wbLo + vLo - lo;
    const unsigned long long exHi = wbHi + vHi - hi;

    unsigned long long obLo = 0, obHi = 0;
    int run = 0;
#pragma unroll
    for (int b = 0; b < NB; ++b) {
        unsigned long long r16 = (unsigned long long)(run & 0xFFFF);
        if (b < 4) obLo |= r16 << (16 * b); else obHi |= r16 << (16 * (b - 4));
        int tb = (b < 4) ? (int)((gLo >> (16 * b)) & 0xFFFFull)
                         : (int)((gHi >> (16 * (b - 4))) & 0xFFFFull);
        run += tb;
    }
    unsigned long long curLo = exLo + obLo;
    unsigned long long curHi = exHi + obHi;

#pragma unroll
    for (int j = 0; j < PER_THREAD; ++j) {
        int b = p[j] >> shift; b = b > (NB - 1) ? (NB - 1) : b;
        int sh = 16 * (b & 3);
        int idx = (b < 4) ? (int)((curLo >> sh) & 0xFFFFull)
                          : (int)((curHi >> sh) & 0xFFFFull);
        buf[idx] = make_int2(p[j], c[j]);
        if (b < 4) curLo += 1ull << sh; else curHi += 1ull << sh;
    }
    __syncthreads();

#pragma unroll
    for (int b = 0; b < NB; ++b) {
        int bib = (b < 4) ? (int)((obLo >> (16 * b)) & 0xFFFFull)
                          : (int)((obHi >> (16 * (b - 4))) & 0xFFFFull);
        int tb  = (b < 4) ? (int)((gLo >> (16 * b)) & 0xFFFFull)
                          : (int)((gHi >> (16 * (b - 4))) & 0xFFFFull);
        long long go = s_goff[b];
        for (int i = tid; i < tb; i += THREADS) {
            int2 v = buf[bib + i];
            vint2 w; w.x = v.x; w.y = v.y;
            __builtin_nontemporal_store(w, (vint2*)(pairs + 2 * (go + i)));
        }
    }
}

// ---------------------------------------------------------------- Phase D
// bucket = blockIdx&7 (XCD-pinned; 4 MB x-slice L2-resident). Chunk ownership
// is segment-aligned: entries equal to the nominal-boundary segment belong to
// the chunk holding that segment's first entry. All partial writes are plain
// nt stores; gaps between chunk spans zero-filled. NO global atomics.
__global__ __launch_bounds__(THREADS) void phaseD_gather(
    const float* __restrict__ x, const int* __restrict__ pairs,
    const int* __restrict__ totals, const int* __restrict__ csrSlice,
    int nnzP, float* __restrict__ partials, int partCap)
{
    __shared__ float seg[LDS_SEGS_D];
    const int tid = threadIdx.x;
    const int rel = blockIdx.x & (NB - 1);

    int bbase = 0;
#pragma unroll
    for (int i = 0; i < NB; ++i) {
        int t = totals[i];
        if (i < rel) bbase += pad8(t);
    }
    const int total_b = totals[rel];
    const int segBase = csrSlice[0];
    const int segLastPass = csrSlice[nnzP - 1];
    float* part = partials + (size_t)rel * partCap;

    const int nchunks = (total_b + EPB - 1) / EPB;
    const int jstride = gridDim.x >> 3;

    if (nchunks == 0) {                       // degenerate: empty bucket
        if ((blockIdx.x >> 3) == 0) {
            int span = segLastPass - segBase + 1;
            for (int s = tid; s < span && s < partCap; s += THREADS)
                __builtin_nontemporal_store(0.0f, part + s);
        }
        return;
    }

    for (int j = blockIdx.x >> 3; j < nchunks; j += jstride) {
        const int n0 = j * EPB;
        const int n1 = min(n0 + EPB, total_b);

        int vprev = INT_MIN;
        int s0 = n0;
        if (j > 0) {
            vprev = pairs[2 * (bbase + n0 - 1) + 1];
            while (s0 < total_b && pairs[2 * (bbase + s0) + 1] == vprev) ++s0;
        }
        int e0;
        if (n1 >= total_b) e0 = total_b;
        else {
            const int vend = pairs[2 * (bbase + n1 - 1) + 1];
            e0 = n1;
            while (e0 < total_b && pairs[2 * (bbase + e0) + 1] == vend) ++e0;
        }
        if (s0 >= e0) continue;   // fully absorbed by an earlier chunk

        const int first = pairs[2 * (bbase + s0) + 1];
        const int last  = pairs[2 * (bbase + e0 - 1) + 1];

        // Load pairs (interleaved -> coalesced 512B/wave) + gather once.
        int   cc[PER_THREAD];
        float vv[PER_THREAD];
#pragma unroll
        for (int k = 0; k < PER_THREAD; ++k) {
            const int i = s0 + k * THREADS + tid;
            if (i < e0) {
                vint2 t = __builtin_nontemporal_load(
                    (const vint2*)(pairs + 2 * (bbase + i)));
                cc[k] = t.y;
                vv[k] = x[t.x];               // L2-resident slice gather
            } else { cc[k] = INT_MIN; vv[k] = 0.0f; }
        }

        // Windowed LDS accumulate + flush (1 window in all but ~0 cases).
        for (int wbase = first; wbase <= last; wbase += LDS_SEGS_D) {
            const int wend = min(wbase + LDS_SEGS_D - 1, last);
            for (int s = tid; s < LDS_SEGS_D; s += THREADS) seg[s] = 0.0f;
            __syncthreads();
#pragma unroll
            for (int k = 0; k < PER_THREAD; ++k) {
                const int c = cc[k];
                if (c >= wbase && c <= wend) atomicAdd(&seg[c - wbase], vv[k]);
            }
            // overflow entries past the preloaded 4096 (chunk extension)
            for (int i = s0 + PER_THREAD * THREADS + tid; i < e0; i += THREADS) {
                vint2 t = __builtin_nontemporal_load(
                    (const vint2*)(pairs + 2 * (bbase + i)));
                if (t.y >= wbase && t.y <= wend)
                    atomicAdd(&seg[t.y - wbase], x[t.x]);
            }
            __syncthreads();
            for (int s = wbase + tid; s <= wend; s += THREADS) {
                const int idx = s - segBase;
                if (idx < partCap)
                    __builtin_nontemporal_store(seg[s - wbase], part + idx);
            }
            __syncthreads();
        }

        // Zero-fill the gap before my span (and the bucket tail if last).
        const int fillLo = (j == 0) ? segBase : (vprev + 1);
        for (int s = fillLo + tid; s < first; s += THREADS) {
            const int idx = s - segBase;
            if (idx >= 0 && idx < partCap)
                __builtin_nontemporal_store(0.0f, part + idx);
        }
        if (e0 == total_b) {
            for (int s = last + 1 + tid; s <= segLastPass; s += THREADS) {
                const int idx = s - segBase;
                if (idx < partCap)
                    __builtin_nontemporal_store(0.0f, part + idx);
            }
        }
    }
}

// ---------------------------------------------------------------- Phase E
// out[slice] = sum of 8 bucket partials. Pure streaming; atomics only at the
// two pass-boundary segments (shared with neighbor passes; out memset 0).
__global__ __launch_bounds__(THREADS) void phaseE_reduce(
    const float* __restrict__ partials, int partCap,
    const int* __restrict__ csrSlice, int nnzP, float* __restrict__ out)
{
    const int segBase = csrSlice[0];
    int span = csrSlice[nnzP - 1] - segBase + 1;
    if (span > partCap) span = partCap;       // paranoia clamp
    const int stride = gridDim.x * THREADS;
    for (int s = blockIdx.x * THREADS + threadIdx.x; s < span; s += stride) {
        float sum = 0.0f;
#pragma unroll
        for (int b = 0; b < NB; ++b)
            sum += __builtin_nontemporal_load(partials + (size_t)b * partCap + s);
        if (s == 0 || s == span - 1) atomicAdd(out + segBase + s, sum);
        else __builtin_nontemporal_store(sum, out + segBase + s);
    }
}

// ------------------------------------------------- Fallback (= proven R3)
__global__ __launch_bounds__(THREADS) void fallback_segsum(
    const float* __restrict__ x, const int* __restrict__ ptrs,
    const int* __restrict__ csr, float* __restrict__ out)
{
    __shared__ float seg[LDS_SEGS_FB];
    const int tid = threadIdx.x;
    const long long blk_base = (long long)blockIdx.x * EPB;
    const long long base = blk_base + (long long)tid * PER_THREAD;

    const int seg_base = csr[blk_base];
    const int seg_last = csr[blk_base + EPB - 1];
    const int span = seg_last - seg_base + 1;

    for (int s = tid; s < LDS_SEGS_FB; s += THREADS) seg[s] = 0.0f;

    const vint4* p4 = (const vint4*)(ptrs + base);
    const vint4* c4 = (const vint4*)(csr + base);
    int p[PER_THREAD], c[PER_THREAD];
#pragma unroll
    for (int k = 0; k < PER_THREAD / 4; ++k) {
        vint4 a = __builtin_nontemporal_load(p4 + k);
        vint4 b = __builtin_nontemporal_load(c4 + k);
        p[4 * k + 0] = a.x; p[4 * k + 1] = a.y; p[4 * k + 2] = a.z; p[4 * k + 3] = a.w;
        c[4 * k + 0] = b.x; c[4 * k + 1] = b.y; c[4 * k + 2] = b.z; c[4 * k + 3] = b.w;
    }
    float v[PER_THREAD];
#pragma unroll
    for (int j = 0; j < PER_THREAD; ++j) v[j] = x[p[j]];
    __syncthreads();

    if (span <= LDS_SEGS_FB) {
        float acc = v[0]; int cur = c[0];
#pragma unroll
        for (int j = 1; j < PER_THREAD; ++j) {
            if (c[j] == cur) acc += v[j];
            else { atomicAdd(&seg[cur - seg_base], acc); cur = c[j]; acc = v[j]; }
        }
        atomicAdd(&seg[cur - seg_base], acc);
        __syncthreads();
        for (int s = tid; s < span; s += THREADS) {
            const int g = seg_base + s;
            const float val = seg[s];
            if (s == 0 || g == seg_last) { if (val != 0.0f) atomicAdd(out + g, val); }
            else __builtin_nontemporal_store(val, out + g);
        }
    } else {
        float acc = v[0]; int cur = c[0];
#pragma unroll
        for (int j = 1; j < PER_THREAD; ++j) {
            if (c[j] == cur) acc += v[j];
            else { atomicAdd(out + cur, acc); cur = c[j]; acc = v[j]; }
        }
        atomicAdd(out + cur, acc);
    }
}

extern "C" void kernel_launch(void* const* d_in, const int* in_sizes, int n_in,
                              void* d_out, int out_size, void* d_ws, size_t ws_size,
                              hipStream_t stream) {
    const float* x    = (const float*)d_in[0];
    const int*   ptrs = (const int*)d_in[1];
    const int*   csr  = (const int*)d_in[2];
    float*       out  = (float*)d_out;

    const long long nnz = in_sizes[1];            // 33,554,432
    const int x_size = in_sizes[0];               // 8,388,608

    (void)hipMemsetAsync(d_out, 0, (size_t)out_size * sizeof(float), stream);

    const long long nnzP = nnz / NPASS;           // 8,388,608
    const long long nblocksP = nnzP / EPB;        // 2,048
    const int slice = x_size / NB;                // 1,048,576 (2^20)
    const bool ok_shapes =
        (nnz % ((long long)NPASS * EPB) == 0) && (nblocksP % THREADS == 0) &&
        slice > 0 && ((slice & (slice - 1)) == 0) && (x_size % NB == 0) &&
        nnzP < (long long)INT_MAX / 4;

    const size_t pairsCap   = (size_t)nnzP + 16 * NB;
    const size_t pairsBytes = (pairsCap * 8 + 255) & ~(size_t)255;
    const int    partCap    = out_size / NPASS + 262144;
    const size_t partBytes  = ((size_t)NB * partCap * 4 + 255) & ~(size_t)255;
    const size_t cntBytes   = ((size_t)nblocksP * NB * 4 + 255) & ~(size_t)255;
    const size_t need       = pairsBytes + partBytes + 2 * cntBytes + 512;

    if (ok_shapes && ws_size >= need) {
        char* w = (char*)d_ws;
        int*   pairs    = (int*)w;
        float* partials = (float*)(w + pairsBytes);
        int*   counts   = (int*)(w + pairsBytes + partBytes);
        int*   offB     = (int*)(w + pairsBytes + partBytes + cntBytes);
        int*   totals   = (int*)(w + pairsBytes + partBytes + 2 * cntBytes);
        const int shift = __builtin_ctz((unsigned)slice);   // 20

        for (int g = 0; g < NPASS; ++g) {
            const int* pg = ptrs + (long long)g * nnzP;
            const int* cg = csr  + (long long)g * nnzP;
            phaseA_count  <<<(int)nblocksP, THREADS, 0, stream>>>(pg, counts, shift);
            phaseB_scan   <<<NB,            THREADS, 0, stream>>>(counts, offB, totals, (int)nblocksP);
            phaseC_scatter<<<(int)nblocksP, THREADS, 0, stream>>>(pg, cg, offB, totals, pairs, shift);
            phaseD_gather <<<(int)nblocksP, THREADS, 0, stream>>>(x, pairs, totals, cg, (int)nnzP, partials, partCap);
            phaseE_reduce <<<2048,          THREADS, 0, stream>>>(partials, partCap, cg, (int)nnzP, out);
        }
    } else {
        fallback_segsum<<<(int)(nnz / EPB), THREADS, 0, stream>>>(x, ptrs, csr, out);
    }
}

// Round 6
// 580.873 us; speedup vs baseline: 1.4094x; 1.4094x over previous
//
#include <hip/hip_runtime.h>
#include <hip/hip_bf16.h>
#include <climits>

// out[csr[i]] += x[ptrs[i]]
//   X_SIZE = 8,388,608 f32 (32 MB), NNZ = 33,554,432, N_SEG = 8,388,608, csr SORTED.
//
// R5 post-mortem: gathers were L2-MISS/L3-HIT (slice 4MB == L2, evicted by
// streams) -> 537 MB/pass of L3->L2 line refetch at ~3.9 TB/s = the 138us
// phaseD wall. Dense partials + global-scan phases added 600+ MB of traffic.
//
// R6 design (2 passes over csr-contiguous halves; disjoint out ranges):
//   K1 local-bin: per 4096-entry chunk, stable 16-way bin by ptr>>19 into
//      split ptrB/csrB arrays + per-chunk 16-entry offset table. No global
//      scan, perfectly coalesced I/O.
//   K2 gather: XCD k handles buckets {2k,2k+1} sequentially (slice 2MB =
//      L2/2 -> resident), v[i] = x[ptrB[i]] in binned order. No LDS,
//      32 waves/CU. nt on streams, normal caching on x.
//   K3 combine: block per chunk; csrB+v coalesced; LDS dense window over the
//      chunk's segment span (~1024); interior segs nt-stored (exclusive
//      ownership by csr sortedness), first/last seg atomicAdd.
// Fallback = proven R3 kernel (558us) if ws/shapes don't fit.

#define THREADS 256
#define PER_THREAD 16
#define EPB (THREADS * PER_THREAD)   // 4096 entries per chunk
#define NB 16                        // ptr slices of 2 MB (= L2/2)
#define NPASS 2
#define NWAVE (THREADS / 64)
#define WIN 8192                     // K3 LDS window (32 KB)
#define LDS_SEGS_FB 4096

typedef int   vint4   __attribute__((ext_vector_type(4)));
typedef float vfloat4 __attribute__((ext_vector_type(4)));
typedef unsigned long long u64;

// ---------------------------------------------------------------- K1
// Chunk-local stable 16-way bin. Packed 16-bit x 4 bucket counters in four
// u64s (q0..q3); all register indexing static (nested-if / unrolled).
__global__ __launch_bounds__(THREADS) void k1_localbin(
    const int* __restrict__ ptrs, const int* __restrict__ csr,
    int* __restrict__ ptrB, int* __restrict__ csrB,
    int* __restrict__ offs, int shift)
{
    __shared__ int2 buf[EPB];                 // 32 KB
    __shared__ u64 wq0[NWAVE], wq1[NWAVE], wq2[NWAVE], wq3[NWAVE];

    const int tid = threadIdx.x, lane = tid & 63, wid = tid >> 6;
    const long long cb = (long long)blockIdx.x * EPB;
    const long long base = cb + (long long)tid * PER_THREAD;

    const vint4* p4 = (const vint4*)(ptrs + base);
    const vint4* c4 = (const vint4*)(csr + base);
    int p[PER_THREAD], c[PER_THREAD];
#pragma unroll
    for (int k = 0; k < PER_THREAD / 4; ++k) {
        vint4 a = __builtin_nontemporal_load(p4 + k);
        vint4 b = __builtin_nontemporal_load(c4 + k);
        p[4 * k + 0] = a.x; p[4 * k + 1] = a.y; p[4 * k + 2] = a.z; p[4 * k + 3] = a.w;
        c[4 * k + 0] = b.x; c[4 * k + 1] = b.y; c[4 * k + 2] = b.z; c[4 * k + 3] = b.w;
    }

    // per-thread packed counts
    u64 q0 = 0, q1 = 0, q2 = 0, q3 = 0;
#pragma unroll
    for (int j = 0; j < PER_THREAD; ++j) {
        int b = p[j] >> shift; b = b > (NB - 1) ? (NB - 1) : b;
        u64 one = 1ull << (16 * (b & 3));
        if (b < 8) { if (b < 4) q0 += one; else q1 += one; }
        else       { if (b < 12) q2 += one; else q3 += one; }
    }

    // wave inclusive scans (lane-wise 16-bit adds never carry: sums <= 1024)
    u64 s0 = q0, s1 = q1, s2 = q2, s3 = q3;
#pragma unroll
    for (int d = 1; d < 64; d <<= 1) {
        u64 t0 = __shfl_up(s0, (unsigned)d);
        u64 t1 = __shfl_up(s1, (unsigned)d);
        u64 t2 = __shfl_up(s2, (unsigned)d);
        u64 t3 = __shfl_up(s3, (unsigned)d);
        if (lane >= d) { s0 += t0; s1 += t1; s2 += t2; s3 += t3; }
    }
    if (lane == 63) { wq0[wid] = s0; wq1[wid] = s1; wq2[wid] = s2; wq3[wid] = s3; }
    __syncthreads();

    u64 wb0 = 0, wb1 = 0, wb2 = 0, wb3 = 0;
    u64 g0 = 0, g1 = 0, g2 = 0, g3 = 0;
#pragma unroll
    for (int w = 0; w < NWAVE; ++w) {
        if (w < wid) { wb0 += wq0[w]; wb1 += wq1[w]; wb2 += wq2[w]; wb3 += wq3[w]; }
        g0 += wq0[w]; g1 += wq1[w]; g2 += wq2[w]; g3 += wq3[w];
    }
    const u64 ex0 = wb0 + s0 - q0, ex1 = wb1 + s1 - q1;
    const u64 ex2 = wb2 + s2 - q2, ex3 = wb3 + s3 - q3;

    // block-internal bucket bases (exclusive prefix over 16 buckets)
    u64 ob0 = 0, ob1 = 0, ob2 = 0, ob3 = 0;
    int run = 0;
#pragma unroll
    for (int b = 0; b < NB; ++b) {            // b compile-time (unrolled)
        int sh = 16 * (b & 3);
        u64 r16 = (u64)(run & 0xFFFF);
        int tb;
        if (b < 8) {
            if (b < 4) { ob0 |= r16 << sh; tb = (int)((g0 >> sh) & 0xFFFFull); }
            else       { ob1 |= r16 << sh; tb = (int)((g1 >> sh) & 0xFFFFull); }
        } else {
            if (b < 12) { ob2 |= r16 << sh; tb = (int)((g2 >> sh) & 0xFFFFull); }
            else        { ob3 |= r16 << sh; tb = (int)((g3 >> sh) & 0xFFFFull); }
        }
        run += tb;
    }
    u64 cur0 = ex0 + ob0, cur1 = ex1 + ob1, cur2 = ex2 + ob2, cur3 = ex3 + ob3;

    // stable replay into LDS (binned order)
#pragma unroll
    for (int j = 0; j < PER_THREAD; ++j) {
        int b = p[j] >> shift; b = b > (NB - 1) ? (NB - 1) : b;
        int sh = 16 * (b & 3);
        int idx;
        if (b < 8) {
            if (b < 4) { idx = (int)((cur0 >> sh) & 0xFFFFull); cur0 += 1ull << sh; }
            else       { idx = (int)((cur1 >> sh) & 0xFFFFull); cur1 += 1ull << sh; }
        } else {
            if (b < 12) { idx = (int)((cur2 >> sh) & 0xFFFFull); cur2 += 1ull << sh; }
            else        { idx = (int)((cur3 >> sh) & 0xFFFFull); cur3 += 1ull << sh; }
        }
        buf[idx] = make_int2(p[j], c[j]);
    }
    __syncthreads();

    // linear coalesced write-out into split arrays
    for (int i = tid; i < EPB; i += THREADS) {
        int2 e = buf[i];
        __builtin_nontemporal_store(e.x, ptrB + cb + i);
        __builtin_nontemporal_store(e.y, csrB + cb + i);
    }
    // per-chunk bucket offsets
    if (tid < NB) {
        int sh = 16 * (tid & 3);
        int v;
        if (tid < 8) { if (tid < 4) v = (int)((ob0 >> sh) & 0xFFFFull);
                       else         v = (int)((ob1 >> sh) & 0xFFFFull); }
        else         { if (tid < 12) v = (int)((ob2 >> sh) & 0xFFFFull);
                       else          v = (int)((ob3 >> sh) & 0xFFFFull); }
        offs[blockIdx.x * NB + tid] = v;
    }
}

// ---------------------------------------------------------------- K2
// XCD k (= blockIdx&7) gathers buckets {2k, 2k+1} sequentially: 2 MB x-slice
// stays L2-resident. Streams nt; x normally cached. No LDS -> max occupancy.
__global__ __launch_bounds__(THREADS) void k2_gather(
    const float* __restrict__ x, const int* __restrict__ ptrB,
    const int* __restrict__ offs, float* __restrict__ v, int chunksP)
{
    const int tid = threadIdx.x;
    const int xcd = blockIdx.x & 7;
    const int blk = blockIdx.x >> 3;
    const int nblk = gridDim.x >> 3;

#pragma unroll
    for (int bi = 0; bi < 2; ++bi) {
        const int b = xcd * 2 + bi;
        for (int j = blk; j < chunksP; j += nblk) {
            const int o0 = offs[j * NB + b];
            const int o1 = (b == NB - 1) ? EPB : offs[j * NB + b + 1];
            const long long cbase = (long long)j * EPB;
            for (int i = o0 + tid; i < o1; i += THREADS) {
                int pi = __builtin_nontemporal_load(ptrB + cbase + i);
                float val = x[pi];                        // L2-resident slice
                __builtin_nontemporal_store(val, v + cbase + i);
            }
        }
    }
}

// ---------------------------------------------------------------- K3
// Block per chunk: dense LDS window over the chunk's segment span; interior
// segs exclusively owned (csr sorted) -> nt store; first/last seg atomic.
__global__ __launch_bounds__(THREADS) void k3_combine(
    const int* __restrict__ csrOrig, const int* __restrict__ csrB,
    const float* __restrict__ v, float* __restrict__ out)
{
    __shared__ float win[WIN];
    __shared__ int s_sb, s_sl;

    const int tid = threadIdx.x;
    const long long cb = (long long)blockIdx.x * EPB;

    if (tid == 0) { s_sb = csrOrig[cb]; s_sl = csrOrig[cb + EPB - 1]; }

    // coalesced vector loads of this thread's 16 (seg, val) entries
    const vint4*   c4 = (const vint4*)(csrB + cb + (long long)tid * PER_THREAD);
    const vfloat4* v4 = (const vfloat4*)(v + cb + (long long)tid * PER_THREAD);
    int cc[PER_THREAD]; float vv[PER_THREAD];
#pragma unroll
    for (int k = 0; k < PER_THREAD / 4; ++k) {
        vint4   a = __builtin_nontemporal_load(c4 + k);
        vfloat4 f = __builtin_nontemporal_load(v4 + k);
        cc[4 * k + 0] = a.x; cc[4 * k + 1] = a.y; cc[4 * k + 2] = a.z; cc[4 * k + 3] = a.w;
        vv[4 * k + 0] = f.x; vv[4 * k + 1] = f.y; vv[4 * k + 2] = f.z; vv[4 * k + 3] = f.w;
    }
    __syncthreads();
    const int sb = s_sb, sl = s_sl;

    // windowed (span <= WIN in all but pathological cases -> 1 iteration)
    for (int wb = sb; wb <= sl; wb += WIN) {
        const int we = (wb + WIN - 1 < sl) ? (wb + WIN - 1) : sl;
        const int wlen = we - wb + 1;
        for (int s = tid; s < wlen; s += THREADS) win[s] = 0.0f;
        __syncthreads();

        // run-length compress (equal csr values always share a window)
        float acc = vv[0]; int cur = cc[0];
#pragma unroll
        for (int j = 1; j < PER_THREAD; ++j) {
            if (cc[j] == cur) acc += vv[j];
            else {
                if (cur >= wb && cur <= we) atomicAdd(&win[cur - wb], acc);
                cur = cc[j]; acc = vv[j];
            }
        }
        if (cur >= wb && cur <= we) atomicAdd(&win[cur - wb], acc);
        __syncthreads();

        for (int s = tid; s < wlen; s += THREADS) {
            const int g = wb + s;
            const float val = win[s];
            if (g == sb || g == sl) { if (val != 0.0f) atomicAdd(out + g, val); }
            else __builtin_nontemporal_store(val, out + g);
        }
        __syncthreads();
    }
}

// ------------------------------------------------- Fallback (= proven R3)
__global__ __launch_bounds__(THREADS) void fallback_segsum(
    const float* __restrict__ x, const int* __restrict__ ptrs,
    const int* __restrict__ csr, float* __restrict__ out)
{
    __shared__ float seg[LDS_SEGS_FB];
    const int tid = threadIdx.x;
    const long long blk_base = (long long)blockIdx.x * EPB;
    const long long base = blk_base + (long long)tid * PER_THREAD;

    const int seg_base = csr[blk_base];
    const int seg_last = csr[blk_base + EPB - 1];
    const int span = seg_last - seg_base + 1;

    for (int s = tid; s < LDS_SEGS_FB; s += THREADS) seg[s] = 0.0f;

    const vint4* p4 = (const vint4*)(ptrs + base);
    const vint4* c4 = (const vint4*)(csr + base);
    int p[PER_THREAD], c[PER_THREAD];
#pragma unroll
    for (int k = 0; k < PER_THREAD / 4; ++k) {
        vint4 a = __builtin_nontemporal_load(p4 + k);
        vint4 b = __builtin_nontemporal_load(c4 + k);
        p[4 * k + 0] = a.x; p[4 * k + 1] = a.y; p[4 * k + 2] = a.z; p[4 * k + 3] = a.w;
        c[4 * k + 0] = b.x; c[4 * k + 1] = b.y; c[4 * k + 2] = b.z; c[4 * k + 3] = b.w;
    }
    float v[PER_THREAD];
#pragma unroll
    for (int j = 0; j < PER_THREAD; ++j) v[j] = x[p[j]];
    __syncthreads();

    if (span <= LDS_SEGS_FB) {
        float acc = v[0]; int cur = c[0];
#pragma unroll
        for (int j = 1; j < PER_THREAD; ++j) {
            if (c[j] == cur) acc += v[j];
            else { atomicAdd(&seg[cur - seg_base], acc); cur = c[j]; acc = v[j]; }
        }
        atomicAdd(&seg[cur - seg_base], acc);
        __syncthreads();
        for (int s = tid; s < span; s += THREADS) {
            const int g = seg_base + s;
            const float val = seg[s];
            if (s == 0 || g == seg_last) { if (val != 0.0f) atomicAdd(out + g, val); }
            else __builtin_nontemporal_store(val, out + g);
        }
    } else {
        float acc = v[0]; int cur = c[0];
#pragma unroll
        for (int j = 1; j < PER_THREAD; ++j) {
            if (c[j] == cur) acc += v[j];
            else { atomicAdd(out + cur, acc); cur = c[j]; acc = v[j]; }
        }
        atomicAdd(out + cur, acc);
    }
}

extern "C" void kernel_launch(void* const* d_in, const int* in_sizes, int n_in,
                              void* d_out, int out_size, void* d_ws, size_t ws_size,
                              hipStream_t stream) {
    const float* x    = (const float*)d_in[0];
    const int*   ptrs = (const int*)d_in[1];
    const int*   csr  = (const int*)d_in[2];
    float*       out  = (float*)d_out;

    const long long nnz = in_sizes[1];            // 33,554,432
    const int x_size = in_sizes[0];               // 8,388,608

    (void)hipMemsetAsync(d_out, 0, (size_t)out_size * sizeof(float), stream);

    const long long nnzP = nnz / NPASS;           // 16,777,216
    const long long chunksP = nnzP / EPB;         // 4,096
    const int slice = x_size / NB;                // 524,288 (2 MB)
    const bool ok_shapes =
        (nnz % ((long long)NPASS * EPB) == 0) && slice > 0 &&
        ((slice & (slice - 1)) == 0) && (x_size % NB == 0) &&
        nnzP < (long long)INT_MAX / 2;

    const size_t arrBytes  = ((size_t)nnzP * 4 + 255) & ~(size_t)255;   // each
    const size_t offsBytes = ((size_t)chunksP * NB * 4 + 255) & ~(size_t)255;
    const size_t need      = 3 * arrBytes + offsBytes + 512;            // ~202 MB

    if (ok_shapes && ws_size >= need) {
        char* w = (char*)d_ws;
        int*   ptrB = (int*)w;
        int*   csrB = (int*)(w + arrBytes);
        float* vbuf = (float*)(w + 2 * arrBytes);
        int*   offs = (int*)(w + 3 * arrBytes);
        const int shift = __builtin_ctz((unsigned)slice);   // 19

        for (int g = 0; g < NPASS; ++g) {
            const int* pg = ptrs + (long long)g * nnzP;
            const int* cg = csr  + (long long)g * nnzP;
            k1_localbin<<<(int)chunksP, THREADS, 0, stream>>>(pg, cg, ptrB, csrB, offs, shift);
            k2_gather  <<<4096,         THREADS, 0, stream>>>(x, ptrB, offs, vbuf, (int)chunksP);
            k3_combine <<<(int)chunksP, THREADS, 0, stream>>>(cg, csrB, vbuf, out);
        }
    } else {
        fallback_segsum<<<(int)(nnz / EPB), THREADS, 0, stream>>>(x, ptrs, csr, out);
    }
}

// Round 7
// 546.761 us; speedup vs baseline: 1.4973x; 1.0624x over previous
//
#include <hip/hip_runtime.h>
#include <hip/hip_bf16.h>
#include <climits>

// out[csr[i]] += x[ptrs[i]]
//   X_SIZE = 8,388,608 f32 (32 MB), NNZ = 33,554,432, N_SEG = 8,388,608, csr SORTED.
//
// R6 post-mortem: K2 gather now cache-resident (FETCH 95MB = ptrB+x) but
// STILL 143us/pass: VGPR=8, dependent load->gather->store chain, ~1
// outstanding gather/wave -> latency-bound at ~400cyc/entry.
// R7: K2 rebuilt for MLP: each block = 8 chunks x 1 bucket, flatten the 8
// variable-size segments via an LDS prefix table, each thread owns 8
// INDEPENDENT entries -> 8 gathers in flight. K1/K3 unchanged.

#define THREADS 256
#define PER_THREAD 16
#define EPB (THREADS * PER_THREAD)   // 4096 entries per chunk
#define NB 16                        // ptr slices of 2 MB (= L2/2)
#define NPASS 2
#define NWAVE (THREADS / 64)
#define CPG 8                        // chunks per K2 group
#define K2U 8                        // K2 entries per thread (MLP depth)
#define WIN 8192                     // K3 LDS window (32 KB)
#define LDS_SEGS_FB 4096

typedef int   vint4   __attribute__((ext_vector_type(4)));
typedef float vfloat4 __attribute__((ext_vector_type(4)));
typedef unsigned long long u64;

// ---------------------------------------------------------------- K1
// Chunk-local stable 16-way bin (unchanged from R6).
__global__ __launch_bounds__(THREADS) void k1_localbin(
    const int* __restrict__ ptrs, const int* __restrict__ csr,
    int* __restrict__ ptrB, int* __restrict__ csrB,
    int* __restrict__ offs, int shift)
{
    __shared__ int2 buf[EPB];                 // 32 KB
    __shared__ u64 wq0[NWAVE], wq1[NWAVE], wq2[NWAVE], wq3[NWAVE];

    const int tid = threadIdx.x, lane = tid & 63, wid = tid >> 6;
    const long long cb = (long long)blockIdx.x * EPB;
    const long long base = cb + (long long)tid * PER_THREAD;

    const vint4* p4 = (const vint4*)(ptrs + base);
    const vint4* c4 = (const vint4*)(csr + base);
    int p[PER_THREAD], c[PER_THREAD];
#pragma unroll
    for (int k = 0; k < PER_THREAD / 4; ++k) {
        vint4 a = __builtin_nontemporal_load(p4 + k);
        vint4 b = __builtin_nontemporal_load(c4 + k);
        p[4 * k + 0] = a.x; p[4 * k + 1] = a.y; p[4 * k + 2] = a.z; p[4 * k + 3] = a.w;
        c[4 * k + 0] = b.x; c[4 * k + 1] = b.y; c[4 * k + 2] = b.z; c[4 * k + 3] = b.w;
    }

    u64 q0 = 0, q1 = 0, q2 = 0, q3 = 0;
#pragma unroll
    for (int j = 0; j < PER_THREAD; ++j) {
        int b = p[j] >> shift; b = b > (NB - 1) ? (NB - 1) : b;
        u64 one = 1ull << (16 * (b & 3));
        if (b < 8) { if (b < 4) q0 += one; else q1 += one; }
        else       { if (b < 12) q2 += one; else q3 += one; }
    }

    u64 s0 = q0, s1 = q1, s2 = q2, s3 = q3;
#pragma unroll
    for (int d = 1; d < 64; d <<= 1) {
        u64 t0 = __shfl_up(s0, (unsigned)d);
        u64 t1 = __shfl_up(s1, (unsigned)d);
        u64 t2 = __shfl_up(s2, (unsigned)d);
        u64 t3 = __shfl_up(s3, (unsigned)d);
        if (lane >= d) { s0 += t0; s1 += t1; s2 += t2; s3 += t3; }
    }
    if (lane == 63) { wq0[wid] = s0; wq1[wid] = s1; wq2[wid] = s2; wq3[wid] = s3; }
    __syncthreads();

    u64 wb0 = 0, wb1 = 0, wb2 = 0, wb3 = 0;
    u64 g0 = 0, g1 = 0, g2 = 0, g3 = 0;
#pragma unroll
    for (int w = 0; w < NWAVE; ++w) {
        if (w < wid) { wb0 += wq0[w]; wb1 += wq1[w]; wb2 += wq2[w]; wb3 += wq3[w]; }
        g0 += wq0[w]; g1 += wq1[w]; g2 += wq2[w]; g3 += wq3[w];
    }
    const u64 ex0 = wb0 + s0 - q0, ex1 = wb1 + s1 - q1;
    const u64 ex2 = wb2 + s2 - q2, ex3 = wb3 + s3 - q3;

    u64 ob0 = 0, ob1 = 0, ob2 = 0, ob3 = 0;
    int run = 0;
#pragma unroll
    for (int b = 0; b < NB; ++b) {
        int sh = 16 * (b & 3);
        u64 r16 = (u64)(run & 0xFFFF);
        int tb;
        if (b < 8) {
            if (b < 4) { ob0 |= r16 << sh; tb = (int)((g0 >> sh) & 0xFFFFull); }
            else       { ob1 |= r16 << sh; tb = (int)((g1 >> sh) & 0xFFFFull); }
        } else {
            if (b < 12) { ob2 |= r16 << sh; tb = (int)((g2 >> sh) & 0xFFFFull); }
            else        { ob3 |= r16 << sh; tb = (int)((g3 >> sh) & 0xFFFFull); }
        }
        run += tb;
    }
    u64 cur0 = ex0 + ob0, cur1 = ex1 + ob1, cur2 = ex2 + ob2, cur3 = ex3 + ob3;

#pragma unroll
    for (int j = 0; j < PER_THREAD; ++j) {
        int b = p[j] >> shift; b = b > (NB - 1) ? (NB - 1) : b;
        int sh = 16 * (b & 3);
        int idx;
        if (b < 8) {
            if (b < 4) { idx = (int)((cur0 >> sh) & 0xFFFFull); cur0 += 1ull << sh; }
            else       { idx = (int)((cur1 >> sh) & 0xFFFFull); cur1 += 1ull << sh; }
        } else {
            if (b < 12) { idx = (int)((cur2 >> sh) & 0xFFFFull); cur2 += 1ull << sh; }
            else        { idx = (int)((cur3 >> sh) & 0xFFFFull); cur3 += 1ull << sh; }
        }
        buf[idx] = make_int2(p[j], c[j]);
    }
    __syncthreads();

    for (int i = tid; i < EPB; i += THREADS) {
        int2 e = buf[i];
        __builtin_nontemporal_store(e.x, ptrB + cb + i);
        __builtin_nontemporal_store(e.y, csrB + cb + i);
    }
    if (tid < NB) {
        int sh = 16 * (tid & 3);
        int v;
        if (tid < 8) { if (tid < 4) v = (int)((ob0 >> sh) & 0xFFFFull);
                       else         v = (int)((ob1 >> sh) & 0xFFFFull); }
        else         { if (tid < 12) v = (int)((ob2 >> sh) & 0xFFFFull);
                       else          v = (int)((ob3 >> sh) & 0xFFFFull); }
        offs[blockIdx.x * NB + tid] = v;
    }
}

// ---------------------------------------------------------------- K2
// MLP-rich gather. Block = (xcd bucket pair) x (group of CPG chunks).
// The CPG variable-size bucket segments are flattened via an LDS prefix
// table; thread t owns flat entries {t, t+THREADS, ...}: K2U independent
// gathers in flight. x slice (2 MB) L2-resident per XCD.
__global__ __launch_bounds__(THREADS) void k2_gather(
    const float* __restrict__ x, const int* __restrict__ ptrB,
    const int* __restrict__ offs, float* __restrict__ v, int chunksP)
{
    __shared__ int s_o0[CPG];
    __shared__ int s_pfx[CPG + 1];

    const int tid = threadIdx.x;
    const int xcd = blockIdx.x & 7;
    const int grp = blockIdx.x >> 3;
    const int ngrp = gridDim.x >> 3;
    const int ngroups = chunksP / CPG;

#pragma unroll
    for (int bi = 0; bi < 2; ++bi) {
        const int b = xcd * 2 + bi;
        for (int g = grp; g < ngroups; g += ngrp) {
            const int j0 = g * CPG;
            if (tid < CPG) {
                const int j = j0 + tid;
                const int o0 = offs[j * NB + b];
                const int o1 = (b == NB - 1) ? EPB : offs[j * NB + b + 1];
                s_o0[tid] = o0;
                s_pfx[tid] = o1 - o0;        // count, scanned below
            }
            __syncthreads();
            if (tid == 0) {
                int r = 0;
#pragma unroll
                for (int k = 0; k < CPG; ++k) { int c = s_pfx[k]; s_pfx[k] = r; r += c; }
                s_pfx[CPG] = r;
            }
            __syncthreads();
            const int T = s_pfx[CPG];

            for (int t0 = 0; t0 < T; t0 += THREADS * K2U) {
                long long gi[K2U];
#pragma unroll
                for (int k = 0; k < K2U; ++k) {
                    const int t = t0 + k * THREADS + tid;
                    gi[k] = -1;
                    if (t < T) {
                        int c = 0;
#pragma unroll
                        for (int m = 1; m < CPG; ++m) if (t >= s_pfx[m]) c = m;
                        gi[k] = (long long)(j0 + c) * EPB + s_o0[c] + (t - s_pfx[c]);
                    }
                }
                int pi[K2U];
#pragma unroll
                for (int k = 0; k < K2U; ++k)
                    pi[k] = (gi[k] >= 0) ? __builtin_nontemporal_load(ptrB + gi[k]) : 0;
                float val[K2U];
#pragma unroll
                for (int k = 0; k < K2U; ++k)
                    val[k] = x[pi[k]];                   // independent, 8 in flight
#pragma unroll
                for (int k = 0; k < K2U; ++k)
                    if (gi[k] >= 0) __builtin_nontemporal_store(val[k], v + gi[k]);
            }
            __syncthreads();
        }
    }
}

// ---------------------------------------------------------------- K3
// Block per chunk: dense LDS window over the chunk's segment span; interior
// segs exclusively owned (csr sorted) -> nt store; first/last seg atomic.
__global__ __launch_bounds__(THREADS) void k3_combine(
    const int* __restrict__ csrOrig, const int* __restrict__ csrB,
    const float* __restrict__ v, float* __restrict__ out)
{
    __shared__ float win[WIN];
    __shared__ int s_sb, s_sl;

    const int tid = threadIdx.x;
    const long long cb = (long long)blockIdx.x * EPB;

    if (tid == 0) { s_sb = csrOrig[cb]; s_sl = csrOrig[cb + EPB - 1]; }

    const vint4*   c4 = (const vint4*)(csrB + cb + (long long)tid * PER_THREAD);
    const vfloat4* v4 = (const vfloat4*)(v + cb + (long long)tid * PER_THREAD);
    int cc[PER_THREAD]; float vv[PER_THREAD];
#pragma unroll
    for (int k = 0; k < PER_THREAD / 4; ++k) {
        vint4   a = __builtin_nontemporal_load(c4 + k);
        vfloat4 f = __builtin_nontemporal_load(v4 + k);
        cc[4 * k + 0] = a.x; cc[4 * k + 1] = a.y; cc[4 * k + 2] = a.z; cc[4 * k + 3] = a.w;
        vv[4 * k + 0] = f.x; vv[4 * k + 1] = f.y; vv[4 * k + 2] = f.z; vv[4 * k + 3] = f.w;
    }
    __syncthreads();
    const int sb = s_sb, sl = s_sl;

    for (int wb = sb; wb <= sl; wb += WIN) {
        const int we = (wb + WIN - 1 < sl) ? (wb + WIN - 1) : sl;
        const int wlen = we - wb + 1;
        for (int s = tid; s < wlen; s += THREADS) win[s] = 0.0f;
        __syncthreads();

        float acc = vv[0]; int cur = cc[0];
#pragma unroll
        for (int j = 1; j < PER_THREAD; ++j) {
            if (cc[j] == cur) acc += vv[j];
            else {
                if (cur >= wb && cur <= we) atomicAdd(&win[cur - wb], acc);
                cur = cc[j]; acc = vv[j];
            }
        }
        if (cur >= wb && cur <= we) atomicAdd(&win[cur - wb], acc);
        __syncthreads();

        for (int s = tid; s < wlen; s += THREADS) {
            const int g = wb + s;
            const float val = win[s];
            if (g == sb || g == sl) { if (val != 0.0f) atomicAdd(out + g, val); }
            else __builtin_nontemporal_store(val, out + g);
        }
        __syncthreads();
    }
}

// ------------------------------------------------- Fallback (= proven R3)
__global__ __launch_bounds__(THREADS) void fallback_segsum(
    const float* __restrict__ x, const int* __restrict__ ptrs,
    const int* __restrict__ csr, float* __restrict__ out)
{
    __shared__ float seg[LDS_SEGS_FB];
    const int tid = threadIdx.x;
    const long long blk_base = (long long)blockIdx.x * EPB;
    const long long base = blk_base + (long long)tid * PER_THREAD;

    const int seg_base = csr[blk_base];
    const int seg_last = csr[blk_base + EPB - 1];
    const int span = seg_last - seg_base + 1;

    for (int s = tid; s < LDS_SEGS_FB; s += THREADS) seg[s] = 0.0f;

    const vint4* p4 = (const vint4*)(ptrs + base);
    const vint4* c4 = (const vint4*)(csr + base);
    int p[PER_THREAD], c[PER_THREAD];
#pragma unroll
    for (int k = 0; k < PER_THREAD / 4; ++k) {
        vint4 a = __builtin_nontemporal_load(p4 + k);
        vint4 b = __builtin_nontemporal_load(c4 + k);
        p[4 * k + 0] = a.x; p[4 * k + 1] = a.y; p[4 * k + 2] = a.z; p[4 * k + 3] = a.w;
        c[4 * k + 0] = b.x; c[4 * k + 1] = b.y; c[4 * k + 2] = b.z; c[4 * k + 3] = b.w;
    }
    float v[PER_THREAD];
#pragma unroll
    for (int j = 0; j < PER_THREAD; ++j) v[j] = x[p[j]];
    __syncthreads();

    if (span <= LDS_SEGS_FB) {
        float acc = v[0]; int cur = c[0];
#pragma unroll
        for (int j = 1; j < PER_THREAD; ++j) {
            if (c[j] == cur) acc += v[j];
            else { atomicAdd(&seg[cur - seg_base], acc); cur = c[j]; acc = v[j]; }
        }
        atomicAdd(&seg[cur - seg_base], acc);
        __syncthreads();
        for (int s = tid; s < span; s += THREADS) {
            const int g = seg_base + s;
            const float val = seg[s];
            if (s == 0 || g == seg_last) { if (val != 0.0f) atomicAdd(out + g, val); }
            else __builtin_nontemporal_store(val, out + g);
        }
    } else {
        float acc = v[0]; int cur = c[0];
#pragma unroll
        for (int j = 1; j < PER_THREAD; ++j) {
            if (c[j] == cur) acc += v[j];
            else { atomicAdd(out + cur, acc); cur = c[j]; acc = v[j]; }
        }
        atomicAdd(out + cur, acc);
    }
}

extern "C" void kernel_launch(void* const* d_in, const int* in_sizes, int n_in,
                              void* d_out, int out_size, void* d_ws, size_t ws_size,
                              hipStream_t stream) {
    const float* x    = (const float*)d_in[0];
    const int*   ptrs = (const int*)d_in[1];
    const int*   csr  = (const int*)d_in[2];
    float*       out  = (float*)d_out;

    const long long nnz = in_sizes[1];            // 33,554,432
    const int x_size = in_sizes[0];               // 8,388,608

    (void)hipMemsetAsync(d_out, 0, (size_t)out_size * sizeof(float), stream);

    const long long nnzP = nnz / NPASS;           // 16,777,216
    const long long chunksP = nnzP / EPB;         // 4,096
    const int slice = x_size / NB;                // 524,288 (2 MB)
    const bool ok_shapes =
        (nnz % ((long long)NPASS * EPB) == 0) && slice > 0 &&
        ((slice & (slice - 1)) == 0) && (x_size % NB == 0) &&
        (chunksP % CPG == 0) && nnzP < (long long)INT_MAX / 2;

    const size_t arrBytes  = ((size_t)nnzP * 4 + 255) & ~(size_t)255;   // each
    const size_t offsBytes = ((size_t)chunksP * NB * 4 + 255) & ~(size_t)255;
    const size_t need      = 3 * arrBytes + offsBytes + 512;            // ~202 MB

    if (ok_shapes && ws_size >= need) {
        char* w = (char*)d_ws;
        int*   ptrB = (int*)w;
        int*   csrB = (int*)(w + arrBytes);
        float* vbuf = (float*)(w + 2 * arrBytes);
        int*   offs = (int*)(w + 3 * arrBytes);
        const int shift = __builtin_ctz((unsigned)slice);   // 19

        for (int g = 0; g < NPASS; ++g) {
            const int* pg = ptrs + (long long)g * nnzP;
            const int* cg = csr  + (long long)g * nnzP;
            k1_localbin<<<(int)chunksP, THREADS, 0, stream>>>(pg, cg, ptrB, csrB, offs, shift);
            k2_gather  <<<4096,         THREADS, 0, stream>>>(x, ptrB, offs, vbuf, (int)chunksP);
            k3_combine <<<(int)chunksP, THREADS, 0, stream>>>(cg, csrB, vbuf, out);
        }
    } else {
        fallback_segsum<<<(int)(nnz / EPB), THREADS, 0, stream>>>(x, ptrs, csr, out);
    }
}